// Round 1
// baseline (182.840 us; speedup 1.0000x reference)
//
#include <hip/hip_runtime.h>

// Problem constants (match reference)
#define GS    20
#define PARAM 40
#define NSYS  80           // B * A = 8 * 10
#define NLOC  (GS * PARAM) // 800 unknowns per system
#define NITER 16           // Jacobi sweeps; contraction ~0.49 => ~1e-5 rel err
#define SPAD  41           // padded row stride for S/Ng (odd -> no bank conflicts)

// Solve (I (x) S + M (x) Ng) x = v per system with point-Jacobi, then clip.
// Row equation for block-row i, component p:
//   sum_q S[p][q] X[i][q] + sum_j M[i][j] * sum_q Ng[p][q] X[j][q] = V[i][p]
__global__ __launch_bounds__(256) void gliam_solve(
    const float* __restrict__ mat,   // (NSYS, GS, GS)
    const float* __restrict__ val,   // (NSYS, GS, PARAM)
    const float* __restrict__ S,     // (PARAM, PARAM)
    const float* __restrict__ Ng,    // (PARAM, PARAM)
    float* __restrict__ out)         // (NSYS, GS, PARAM)
{
    __shared__ float sS [PARAM * SPAD];
    __shared__ float sNg[PARAM * SPAD];
    __shared__ float sM [GS * GS];
    __shared__ float sV [NLOC];
    __shared__ float sX [2][NLOC];
    __shared__ float sW [NLOC];      // W[j][p] = sum_q Ng[p][q] X[j][q]
    __shared__ float sRD[PARAM];     // 1 / S[p][p]

    const int sys = blockIdx.x;
    const int t   = threadIdx.x;

    // Stage inputs into LDS (S/Ng padded to stride 41)
    for (int i = t; i < PARAM * PARAM; i += 256) {
        int p = i / PARAM, q = i - p * PARAM;
        sS [p * SPAD + q] = S[i];
        sNg[p * SPAD + q] = Ng[i];
    }
    for (int i = t; i < GS * GS; i += 256) sM[i] = mat[sys * GS * GS + i];
    for (int i = t; i < NLOC;    i += 256) { sV[i] = val[sys * NLOC + i]; sX[0][i] = 0.0f; }
    if (t < PARAM) sRD[t] = 1.0f / S[t * PARAM + t];
    __syncthreads();

    int cur = 0;
    for (int it = 0; it < NITER; ++it) {
        // Step 1: W[j][p] = sum_q Ng[p][q] * X[j][q]   (lanes share j -> X row broadcast)
        for (int e = t; e < NLOC; e += 256) {
            int j = e / PARAM, p = e - j * PARAM;
            const float* xr  = &sX[cur][j * PARAM];
            const float* ngr = &sNg[p * SPAD];
            float acc = 0.0f;
            #pragma unroll
            for (int q = 0; q < PARAM; ++q) acc += ngr[q] * xr[q];
            sW[e] = acc;
        }
        __syncthreads();
        // Step 2: Jacobi update
        for (int e = t; e < NLOC; e += 256) {
            int i = e / PARAM, p = e - i * PARAM;
            const float* xr = &sX[cur][i * PARAM];
            const float* sr = &sS[p * SPAD];
            float acc = sV[e];
            #pragma unroll
            for (int q = 0; q < PARAM; ++q) acc -= sr[q] * xr[q];
            acc += sr[p] * xr[p];            // remove diagonal term (Jacobi)
            const float* mr = &sM[i * GS];
            #pragma unroll
            for (int j = 0; j < GS; ++j) acc -= mr[j] * sW[j * PARAM + p];
            sX[cur ^ 1][e] = acc * sRD[p];
        }
        __syncthreads();
        cur ^= 1;
    }

    // advrelu with lo=-1, hi=1 == clip(x, -1, 1); write out
    for (int e = t; e < NLOC; e += 256) {
        float x = sX[cur][e];
        x = fminf(fmaxf(x, -1.0f), 1.0f);
        out[sys * NLOC + e] = x;
    }
}

extern "C" void kernel_launch(void* const* d_in, const int* in_sizes, int n_in,
                              void* d_out, int out_size, void* d_ws, size_t ws_size,
                              hipStream_t stream) {
    const float* mat = (const float*)d_in[0];  // 8*10*20*20 = 32000
    const float* val = (const float*)d_in[1];  // 8*10*20*40 = 64000
    const float* S   = (const float*)d_in[2];  // 40*40
    const float* Ng  = (const float*)d_in[3];  // 40*40
    float* out = (float*)d_out;                // 64000 f32

    gliam_solve<<<NSYS, 256, 0, stream>>>(mat, val, S, Ng, out);
}

// Round 2
// 127.560 us; speedup vs baseline: 1.4334x; 1.4334x over previous
//
#include <hip/hip_runtime.h>

// Problem constants (match reference)
#define GS    20
#define PARAM 40
#define NSYS  80             // B * A = 8 * 10
#define NLOC  (GS * PARAM)   // 800 unknowns per system
#define NITER 15             // + x0 = D^-1 v  ==  16 Jacobi sweeps from zero
#define NTHREADS 832         // 13 waves; threads 800..831 idle (barrier-only)

// Solve (I (x) S + M (x) Ng) x = v per system with point-Jacobi, then clip to [-1,1].
// Row eq (block-row i, comp p):  S x_i + sum_j M[i,j] Ng x_j = v_i
// Reassociate: sum_j M[i,j] (Ng x_j) = Ng Z_i with Z_i = sum_j M[i,j] x_j.
// Jacobi (D = diag(S), folded into rows once):
//   x'_{i,p} = v'_{i,p} - S'off[p,:]·x_i - Ng'[p,:]·Z_i
__global__ __launch_bounds__(NTHREADS) void gliam_solve(
    const float* __restrict__ mat,   // (NSYS, GS, GS)
    const float* __restrict__ val,   // (NSYS, GS, PARAM)
    const float* __restrict__ S,     // (PARAM, PARAM)
    const float* __restrict__ Ng,    // (PARAM, PARAM)
    float* __restrict__ out)         // (NSYS, GS, PARAM)
{
    __shared__ float  sS [PARAM * PARAM];
    __shared__ float  sNg[PARAM * PARAM];
    __shared__ float  sM [GS * GS];
    __shared__ float4 sX [2][NLOC / 4];  // double-buffered state
    __shared__ float4 sZ [NLOC / 4];     // Z = M·X

    const int sys = blockIdx.x;
    const int t   = threadIdx.x;

    // ---- stage inputs (coalesced) ----
    for (int idx = t; idx < PARAM * PARAM; idx += NTHREADS) {
        sS [idx] = S [idx];
        sNg[idx] = Ng[idx];
    }
    for (int idx = t; idx < GS * GS; idx += NTHREADS) sM[idx] = mat[sys * GS * GS + idx];
    __syncthreads();

    const int i = t / PARAM;  // block-row 0..19   (valid for t < 800)
    const int p = t % PARAM;  // component 0..39

    // ---- iteration-invariant per-thread state: D^-1-folded S/Ng rows in VGPRs ----
    float4 srow[10], nrow[10];
    float  vreg = 0.0f;
    if (t < NLOC) {
        const float rd = 1.0f / sS[p * PARAM + p];
        const float4* Srow4 = (const float4*)&sS [p * PARAM];  // 160B rows: 16B aligned
        const float4* Nrow4 = (const float4*)&sNg[p * PARAM];
        #pragma unroll
        for (int k = 0; k < 10; ++k) {
            float4 a = Srow4[k]; a.x *= rd; a.y *= rd; a.z *= rd; a.w *= rd; srow[k] = a;
            float4 b = Nrow4[k]; b.x *= rd; b.y *= rd; b.z *= rd; b.w *= rd; nrow[k] = b;
        }
        ((float*)&srow[p >> 2])[p & 3] = 0.0f;   // remove diagonal (Jacobi off-diag part)
        vreg = val[sys * NLOC + t] * rd;          // v' = D^-1 v
        ((float*)sX[0])[t] = vreg;                // x0 = v'  (== one free sweep from zero)
    }
    __syncthreads();

    int cur = 0;
    float xnew = 0.0f;
    for (int it = 0; it < NITER; ++it) {
        // ---- step 1: Z[i][q4] = sum_j M[i,j] * X[j][q4]  (200 threads, float4) ----
        if (t < NLOC / 4) {
            const int zi = t / 10, c = t - zi * 10;
            const float* mr = &sM[zi * GS];
            float4 acc = make_float4(0.f, 0.f, 0.f, 0.f);
            #pragma unroll
            for (int j = 0; j < GS; ++j) {
                const float  m = mr[j];            // broadcast (few addrs/wave)
                const float4 x = sX[cur][j * 10 + c];  // lane-stride-1 float4: conflict-free
                acc.x += m * x.x; acc.y += m * x.y; acc.z += m * x.z; acc.w += m * x.w;
            }
            sZ[t] = acc;
        }
        __syncthreads();

        // ---- step 2: x'_{i,p} = v' - S'row_p · x_i - Ng'row_p · Z_i ----
        if (t < NLOC) {
            const float4* xr = &sX[cur][i * 10];   // broadcast rows (2 addrs/wave = free)
            const float4* zr = &sZ[i * 10];
            float accS = 0.0f, accN = 0.0f;
            #pragma unroll
            for (int k = 0; k < 10; ++k) {
                const float4 x = xr[k];
                const float4 z = zr[k];
                accS += srow[k].x * x.x + srow[k].y * x.y + srow[k].z * x.z + srow[k].w * x.w;
                accN += nrow[k].x * z.x + nrow[k].y * z.y + nrow[k].z * z.z + nrow[k].w * z.w;
            }
            xnew = vreg - accS - accN;
            ((float*)sX[cur ^ 1])[t] = xnew;       // stride-1 write: conflict-free
        }
        __syncthreads();
        cur ^= 1;
    }

    // ---- epilogue: advrelu(lo=-1,hi=1) == clip ----
    if (t < NLOC) {
        out[sys * NLOC + t] = fminf(fmaxf(xnew, -1.0f), 1.0f);
    }
}

extern "C" void kernel_launch(void* const* d_in, const int* in_sizes, int n_in,
                              void* d_out, int out_size, void* d_ws, size_t ws_size,
                              hipStream_t stream) {
    const float* mat = (const float*)d_in[0];  // 8*10*20*20 = 32000
    const float* val = (const float*)d_in[1];  // 8*10*20*40 = 64000
    const float* S   = (const float*)d_in[2];  // 40*40
    const float* Ng  = (const float*)d_in[3];  // 40*40
    float* out = (float*)d_out;                // 64000 f32

    gliam_solve<<<NSYS, NTHREADS, 0, stream>>>(mat, val, S, Ng, out);
}

// Round 3
// 109.380 us; speedup vs baseline: 1.6716x; 1.1662x over previous
//
#include <hip/hip_runtime.h>

// Problem constants (match reference)
#define GS    20
#define PARAM 40
#define NSYS  80             // B * A = 8 * 10
#define NLOC  (GS * PARAM)   // 800 unknowns per system
#define NIT   13             // + x0 = D^-1 v  ==  14 Jacobi sweeps from zero
#define NTH   400            // 6.25 waves; each thread owns 2 elements

// Point-Jacobi on (I (x) S + M (x) Ng) x = v, then clip to [-1,1].
// Phase 1: Z_i = sum_j M[i,j] x_j (200 threads, float4, M rows in VGPRs)
// Phase 2: x'_{i,p} = v'_{i,p} - S'off[p,:]·x_i - Ng'[p,:]·Z_i
//          (register-blocked x2: thread (i,p) does p and p+20, sharing the
//           broadcast x_i / Z_i LDS reads; S/Ng rows live in VGPRs, D^-1 folded)
__global__ __launch_bounds__(NTH) void gliam_solve(
    const float* __restrict__ mat,   // (NSYS, GS, GS)
    const float* __restrict__ val,   // (NSYS, GS, PARAM)
    const float* __restrict__ S,     // (PARAM, PARAM)
    const float* __restrict__ Ng,    // (PARAM, PARAM)
    float* __restrict__ out)         // (NSYS, GS, PARAM)
{
    __shared__ float4 sS [PARAM * 11];   // padded stride 44 floats (11 float4)
    __shared__ float4 sNg[PARAM * 11];
    __shared__ float  sM [GS * GS];
    __shared__ float4 sX [2][NLOC / 4];  // double-buffered state
    __shared__ float4 sZ [NLOC / 4];     // Z = M·X

    const int sys = blockIdx.x;
    const int t   = threadIdx.x;

    // ---- stage inputs (S/Ng padded to 44-float rows for conflict-light reg loads) ----
    const float4* gS  = (const float4*)S;
    const float4* gNg = (const float4*)Ng;
    for (int idx = t; idx < 400; idx += NTH) {
        int p = idx / 10, k = idx - p * 10;
        sS [p * 11 + k] = gS [idx];
        sNg[p * 11 + k] = gNg[idx];
    }
    for (int idx = t; idx < GS * GS; idx += NTH) sM[idx] = mat[sys * GS * GS + idx];
    __syncthreads();

    const int i  = t / 20;          // block-row 0..19
    const int p  = t - i * 20;      // first component 0..19 (second is p+20)
    const int p2 = p + 20;

    // ---- iteration-invariant per-thread state (VGPRs), D^-1 folded ----
    float4 sr0[10], nr0[10], sr1[10], nr1[10];
    float  v0, v1;
    {
        const float rd0 = 1.0f / ((const float*)&sS[p  * 11])[p ];
        const float rd1 = 1.0f / ((const float*)&sS[p2 * 11])[p2];
        #pragma unroll
        for (int k = 0; k < 10; ++k) {
            const int q0 = 4 * k;
            float4 a = sS [p  * 11 + k];
            float4 b = sS [p2 * 11 + k];
            float4 c = sNg[p  * 11 + k];
            float4 d = sNg[p2 * 11 + k];
            // scale by 1/diag and zero the diagonal entry (Jacobi off-diag)
            a.x = (q0 + 0 == p ) ? 0.f : a.x * rd0;
            a.y = (q0 + 1 == p ) ? 0.f : a.y * rd0;
            a.z = (q0 + 2 == p ) ? 0.f : a.z * rd0;
            a.w = (q0 + 3 == p ) ? 0.f : a.w * rd0;
            b.x = (q0 + 0 == p2) ? 0.f : b.x * rd1;
            b.y = (q0 + 1 == p2) ? 0.f : b.y * rd1;
            b.z = (q0 + 2 == p2) ? 0.f : b.z * rd1;
            b.w = (q0 + 3 == p2) ? 0.f : b.w * rd1;
            c.x *= rd0; c.y *= rd0; c.z *= rd0; c.w *= rd0;
            d.x *= rd1; d.y *= rd1; d.z *= rd1; d.w *= rd1;
            sr0[k] = a; sr1[k] = b; nr0[k] = c; nr1[k] = d;
        }
        v0 = val[sys * NLOC + i * PARAM + p ] * rd0;   // v' = D^-1 v
        v1 = val[sys * NLOC + i * PARAM + p2] * rd1;
        ((float*)sX[0])[i * PARAM + p ] = v0;          // x0 = v'
        ((float*)sX[0])[i * PARAM + p2] = v1;
    }

    // ---- phase-1 threads keep their M row in VGPRs ----
    const int zi = t / 10, c = t - zi * 10;            // valid for t < 200
    float mrow[20];
    if (t < 200) {
        #pragma unroll
        for (int j = 0; j < GS; ++j) mrow[j] = sM[zi * GS + j];  // broadcast reads
    }
    __syncthreads();

    int cur = 0;
    for (int it = 0; it < NIT; ++it) {
        // ---- phase 1: Z[zi][c4] = sum_j M[zi,j] * X[j][c4] ----
        if (t < 200) {
            float4 acc = make_float4(0.f, 0.f, 0.f, 0.f);
            #pragma unroll
            for (int j = 0; j < GS; ++j) {
                const float  m = mrow[j];
                const float4 x = sX[cur][j * 10 + c];   // <=2-way banked: free
                acc.x += m * x.x; acc.y += m * x.y; acc.z += m * x.z; acc.w += m * x.w;
            }
            sZ[t] = acc;                                 // stride-1 float4 write
        }
        __syncthreads();

        // ---- phase 2: two outputs per thread sharing x_i / Z_i reads ----
        const float4* xr = &sX[cur][i * 10];   // broadcast rows
        const float4* zr = &sZ[i * 10];
        float a0 = 0.f, a1 = 0.f, b0 = 0.f, b1 = 0.f;
        #pragma unroll
        for (int k = 0; k < 10; ++k) {
            const float4 x = xr[k];
            const float4 z = zr[k];
            a0 += sr0[k].x * x.x + sr0[k].y * x.y + sr0[k].z * x.z + sr0[k].w * x.w;
            b0 += nr0[k].x * z.x + nr0[k].y * z.y + nr0[k].z * z.z + nr0[k].w * z.w;
            a1 += sr1[k].x * x.x + sr1[k].y * x.y + sr1[k].z * x.z + sr1[k].w * x.w;
            b1 += nr1[k].x * z.x + nr1[k].y * z.y + nr1[k].z * z.z + nr1[k].w * z.w;
        }
        const float x0n = v0 - a0 - b0;
        const float x1n = v1 - a1 - b1;
        if (it == NIT - 1) {
            // epilogue: advrelu(lo=-1,hi=1) == clip; store from registers
            out[sys * NLOC + i * PARAM + p ] = fminf(fmaxf(x0n, -1.f), 1.f);
            out[sys * NLOC + i * PARAM + p2] = fminf(fmaxf(x1n, -1.f), 1.f);
        } else {
            ((float*)sX[cur ^ 1])[i * PARAM + p ] = x0n;
            ((float*)sX[cur ^ 1])[i * PARAM + p2] = x1n;
        }
        __syncthreads();
        cur ^= 1;
    }
}

extern "C" void kernel_launch(void* const* d_in, const int* in_sizes, int n_in,
                              void* d_out, int out_size, void* d_ws, size_t ws_size,
                              hipStream_t stream) {
    const float* mat = (const float*)d_in[0];  // 8*10*20*20 = 32000
    const float* val = (const float*)d_in[1];  // 8*10*20*40 = 64000
    const float* S   = (const float*)d_in[2];  // 40*40
    const float* Ng  = (const float*)d_in[3];  // 40*40
    float* out = (float*)d_out;                // 64000 f32

    gliam_solve<<<NSYS, NTH, 0, stream>>>(mat, val, S, Ng, out);
}

// Round 4
// 70.249 us; speedup vs baseline: 2.6027x; 1.5570x over previous
//
#include <hip/hip_runtime.h>

// Problem constants (match reference)
#define GS    20
#define PARAM 40
#define NSYS  80             // B * A = 8 * 10
#define NLOC  (GS * PARAM)   // 800 unknowns per system
#define NTH   400
#define INNER 7              // Jacobi sweeps for G=S^-1 Ng, c=S^-1 v (rho~0.34); MUST be odd
#define OUTER 5              // block-preconditioned sweeps (rho ~ 0.15-0.25)

// Solve (I (x) S + M (x) Ng) x = v, then clip to [-1,1].
// Block form, row i:  x_i = S^-1 v_i - (S^-1 Ng) sum_j M[i,j] x_j  =  c_i - G z_i
// Setup (inner): G and c via point-Jacobi on S (S' rows in VGPRs, G column-major in LDS).
// Outer: phase1 Z = M X (float4), phase2 x' = c - G Z (G rows in VGPRs).
__global__ __launch_bounds__(NTH) void gliam_solve(
    const float* __restrict__ mat,   // (NSYS, GS, GS)
    const float* __restrict__ val,   // (NSYS, GS, PARAM)
    const float* __restrict__ S,     // (PARAM, PARAM)
    const float* __restrict__ Ng,    // (PARAM, PARAM)
    float* __restrict__ out)         // (NSYS, GS, PARAM)
{
    __shared__ float4 sSoff[PARAM * 11];   // D^-1 S, diag zeroed, rows padded to 44 floats
    __shared__ float4 sNgP [PARAM * 11];   // raw Ng, padded
    __shared__ float  sRD  [PARAM];        // 1 / S[p][p]
    __shared__ float  sM   [GS * GS];
    __shared__ float4 sGc  [2][PARAM * 11]; // G column-major: col u at [u*11 .. u*11+9]
    __shared__ float4 sXv  [2][NLOC / 4];   // state X (also c-iteration buffer)
    __shared__ float4 sZ   [NLOC / 4];      // Z = M·X

    const int sys = blockIdx.x;
    const int t   = threadIdx.x;
    const int pb  = t % 10;   // float4 row-block: rows 4pb..4pb+3
    const int u   = t / 10;   // 0..39: G column index; (u<20) also c system-row

    // ---- stage + fold D^-1 into S rows (each thread scales what it stages) ----
    {
        const float rd = 1.0f / S[u * PARAM + u];    // diag of row u
        float4 a = ((const float4*)S)[t];            // row u, float4 block pb
        a.x *= rd; a.y *= rd; a.z *= rd; a.w *= rd;
        if (pb == (u >> 2)) ((float*)&a)[u & 3] = 0.0f;   // zero diagonal entry
        sSoff[u * 11 + pb] = a;
        sNgP [u * 11 + pb] = ((const float4*)Ng)[t];
    }
    if (t < PARAM) sRD[t] = 1.0f / S[t * PARAM + t];
    sM[t] = mat[sys * GS * GS + t];                  // GS*GS == NTH == 400
    __syncthreads();

    // ---- per-thread registers: S' rows 4pb..4pb+3; Ngd/Vd constants for column u ----
    float4 sr0[10], sr1[10], sr2[10], sr3[10];
    float4 ngd, vd = make_float4(0.f, 0.f, 0.f, 0.f);
    {
        #pragma unroll
        for (int k = 0; k < 10; ++k) {
            sr0[k] = sSoff[(4*pb+0)*11 + k];
            sr1[k] = sSoff[(4*pb+1)*11 + k];
            sr2[k] = sSoff[(4*pb+2)*11 + k];
            sr3[k] = sSoff[(4*pb+3)*11 + k];
        }
        const float* Ngf = (const float*)sNgP;
        const float rd0 = sRD[4*pb+0], rd1 = sRD[4*pb+1],
                    rd2 = sRD[4*pb+2], rd3 = sRD[4*pb+3];
        ngd.x = Ngf[(4*pb+0)*44 + u] * rd0;
        ngd.y = Ngf[(4*pb+1)*44 + u] * rd1;
        ngd.z = Ngf[(4*pb+2)*44 + u] * rd2;
        ngd.w = Ngf[(4*pb+3)*44 + u] * rd3;
        sGc[0][u*11 + pb] = ngd;                     // G0 = D^-1 Ng (column-major)
        if (u < GS) {
            const float4 v4 = *(const float4*)&val[sys*NLOC + u*PARAM + 4*pb];
            vd.x = v4.x * rd0; vd.y = v4.y * rd1; vd.z = v4.z * rd2; vd.w = v4.w * rd3;
            sXv[0][u*10 + pb] = vd;                  // c0 = D^-1 v
        }
    }
    __syncthreads();

    // ---- inner sweeps: G <- Ngd - S'off G ;  c <- Vd - S'off c ----
    for (int s = 0; s < INNER; ++s) {
        const int cur = s & 1, nxt = cur ^ 1;
        float4 accG = ngd;
        float4 accC = vd;
        const float4* gcol = &sGc[cur][u * 11];
        #pragma unroll
        for (int k = 0; k < 10; ++k) {
            const float4 g = gcol[k];
            accG.x -= sr0[k].x*g.x + sr0[k].y*g.y + sr0[k].z*g.z + sr0[k].w*g.w;
            accG.y -= sr1[k].x*g.x + sr1[k].y*g.y + sr1[k].z*g.z + sr1[k].w*g.w;
            accG.z -= sr2[k].x*g.x + sr2[k].y*g.y + sr2[k].z*g.z + sr2[k].w*g.w;
            accG.w -= sr3[k].x*g.x + sr3[k].y*g.y + sr3[k].z*g.z + sr3[k].w*g.w;
        }
        if (u < GS) {
            const float4* ccol = &sXv[cur][u * 10];
            #pragma unroll
            for (int k = 0; k < 10; ++k) {
                const float4 c = ccol[k];
                accC.x -= sr0[k].x*c.x + sr0[k].y*c.y + sr0[k].z*c.z + sr0[k].w*c.w;
                accC.y -= sr1[k].x*c.x + sr1[k].y*c.y + sr1[k].z*c.z + sr1[k].w*c.w;
                accC.z -= sr2[k].x*c.x + sr2[k].y*c.y + sr2[k].z*c.z + sr2[k].w*c.w;
                accC.w -= sr3[k].x*c.x + sr3[k].y*c.y + sr3[k].z*c.z + sr3[k].w*c.w;
            }
        }
        sGc[nxt][u*11 + pb] = accG;
        if (u < GS) sXv[nxt][u*10 + pb] = accC;
        __syncthreads();
    }
    const int fin = INNER & 1;   // final G / c buffer index (== 1 for odd INNER)

    // ---- outer-loop registers: G rows p, p+20; c values; M row ----
    const int i = t / GS;        // block-row 0..19
    const int p = t % GS;        // component 0..19; partner p+20
    float4 gr0[10], gr1[10];
    {
        const float* Gf = (const float*)sGc[fin];    // G[r][q] at [q*44 + r]
        #pragma unroll
        for (int k = 0; k < 10; ++k) {
            gr0[k].x = Gf[(4*k+0)*44 + p];  gr0[k].y = Gf[(4*k+1)*44 + p];
            gr0[k].z = Gf[(4*k+2)*44 + p];  gr0[k].w = Gf[(4*k+3)*44 + p];
            gr1[k].x = Gf[(4*k+0)*44 + p+20]; gr1[k].y = Gf[(4*k+1)*44 + p+20];
            gr1[k].z = Gf[(4*k+2)*44 + p+20]; gr1[k].w = Gf[(4*k+3)*44 + p+20];
        }
    }
    const float c0 = ((const float*)sXv[fin])[i*PARAM + p];
    const float c1 = ((const float*)sXv[fin])[i*PARAM + p + 20];
    float mrow[GS];
    if (t < 200) {
        const int zi = t / 10;
        #pragma unroll
        for (int j = 0; j < GS; ++j) mrow[j] = sM[zi*GS + j];
    }
    // (reads only — data is final behind the last inner barrier; x0 = c already in sXv[fin])

    int cur = fin;
    for (int it = 0; it < OUTER; ++it) {
        // phase 1: Z[zi][cc4] = sum_j M[zi,j] * X[j][cc4]
        if (t < 200) {
            const int zi = t / 10, cc = t - (t/10)*10;
            const float4* X4 = sXv[cur];
            float4 acc = make_float4(0.f, 0.f, 0.f, 0.f);
            #pragma unroll
            for (int j = 0; j < GS; ++j) {
                const float  m = mrow[j];
                const float4 x = X4[j*10 + cc];
                acc.x += m*x.x; acc.y += m*x.y; acc.z += m*x.z; acc.w += m*x.w;
            }
            sZ[t] = acc;
        }
        __syncthreads();
        // phase 2: x'_{i,p} = c - Grow_p · Z_i  (two outputs share Z_i reads)
        const float4* Z4 = &sZ[i*10];
        float a0 = 0.f, a1 = 0.f;
        #pragma unroll
        for (int k = 0; k < 10; ++k) {
            const float4 z = Z4[k];
            a0 += gr0[k].x*z.x + gr0[k].y*z.y + gr0[k].z*z.z + gr0[k].w*z.w;
            a1 += gr1[k].x*z.x + gr1[k].y*z.y + gr1[k].z*z.z + gr1[k].w*z.w;
        }
        const float x0n = c0 - a0, x1n = c1 - a1;
        if (it == OUTER - 1) {
            // epilogue: advrelu(lo=-1,hi=1) == clip
            out[sys*NLOC + i*PARAM + p   ] = fminf(fmaxf(x0n, -1.f), 1.f);
            out[sys*NLOC + i*PARAM + p+20] = fminf(fmaxf(x1n, -1.f), 1.f);
        } else {
            ((float*)sXv[cur ^ 1])[i*PARAM + p   ] = x0n;
            ((float*)sXv[cur ^ 1])[i*PARAM + p+20] = x1n;
            __syncthreads();
            cur ^= 1;
        }
    }
}

extern "C" void kernel_launch(void* const* d_in, const int* in_sizes, int n_in,
                              void* d_out, int out_size, void* d_ws, size_t ws_size,
                              hipStream_t stream) {
    const float* mat = (const float*)d_in[0];  // 8*10*20*20 = 32000
    const float* val = (const float*)d_in[1];  // 8*10*20*40 = 64000
    const float* S   = (const float*)d_in[2];  // 40*40
    const float* Ng  = (const float*)d_in[3];  // 40*40
    float* out = (float*)d_out;                // 64000 f32

    gliam_solve<<<NSYS, NTH, 0, stream>>>(mat, val, S, Ng, out);
}

// Round 5
// 69.023 us; speedup vs baseline: 2.6490x; 1.0178x over previous
//
#include <hip/hip_runtime.h>

// Problem constants (match reference)
#define GS    20
#define PARAM 40
#define NSYS  80             // B * A = 8 * 10
#define NLOC  (GS * PARAM)   // 800 unknowns per system
#define NTH   400
#define INNER 5              // Jacobi sweeps for G=S^-1 Ng, c=S^-1 v (||B||~0.34); MUST be odd
#define OUTER 4              // block-preconditioned sweeps (rho ~ 0.15)

// Solve (I (x) S + M (x) Ng) x = v, then clip to [-1,1].
// Block form, row i:  x_i = S^-1 v_i - (S^-1 Ng) sum_j M[i,j] x_j  =  c_i - G z_i
// Setup (inner): G and c via point-Jacobi on S (S' rows in VGPRs, G column-major in LDS).
// Outer: phase1 Z = M X (float4), phase2 x' = c - G Z (G rows in VGPRs).
__global__ __launch_bounds__(NTH) void gliam_solve(
    const float* __restrict__ mat,   // (NSYS, GS, GS)
    const float* __restrict__ val,   // (NSYS, GS, PARAM)
    const float* __restrict__ S,     // (PARAM, PARAM)
    const float* __restrict__ Ng,    // (PARAM, PARAM)
    float* __restrict__ out)         // (NSYS, GS, PARAM)
{
    __shared__ float4 sSoff[PARAM * 11];   // D^-1 S, diag zeroed, rows padded to 44 floats
    __shared__ float4 sNgP [PARAM * 11];   // raw Ng, padded
    __shared__ float  sRD  [PARAM];        // 1 / S[p][p]
    __shared__ float  sM   [GS * GS];
    __shared__ float4 sGc  [2][PARAM * 11]; // G column-major: col u at [u*11 .. u*11+9]
    __shared__ float4 sXv  [2][NLOC / 4];   // state X (also c-iteration buffer)
    __shared__ float4 sZ   [NLOC / 4];      // Z = M·X

    const int sys = blockIdx.x;
    const int t   = threadIdx.x;
    const int pb  = t % 10;   // float4 row-block: rows 4pb..4pb+3
    const int u   = t / 10;   // 0..39: G column index; (u<20) also c system-row

    // ---- stage + fold D^-1 into S rows (each thread scales what it stages) ----
    {
        const float rd = 1.0f / S[u * PARAM + u];    // diag of row u
        float4 a = ((const float4*)S)[t];            // row u, float4 block pb
        a.x *= rd; a.y *= rd; a.z *= rd; a.w *= rd;
        if (pb == (u >> 2)) ((float*)&a)[u & 3] = 0.0f;   // zero diagonal entry
        sSoff[u * 11 + pb] = a;
        sNgP [u * 11 + pb] = ((const float4*)Ng)[t];
    }
    if (t < PARAM) sRD[t] = 1.0f / S[t * PARAM + t];
    sM[t] = mat[sys * GS * GS + t];                  // GS*GS == NTH == 400
    __syncthreads();

    // ---- per-thread registers: S' rows 4pb..4pb+3; Ngd/Vd constants for column u ----
    float4 sr0[10], sr1[10], sr2[10], sr3[10];
    float4 ngd, vd = make_float4(0.f, 0.f, 0.f, 0.f);
    {
        #pragma unroll
        for (int k = 0; k < 10; ++k) {
            sr0[k] = sSoff[(4*pb+0)*11 + k];
            sr1[k] = sSoff[(4*pb+1)*11 + k];
            sr2[k] = sSoff[(4*pb+2)*11 + k];
            sr3[k] = sSoff[(4*pb+3)*11 + k];
        }
        const float* Ngf = (const float*)sNgP;
        const float rd0 = sRD[4*pb+0], rd1 = sRD[4*pb+1],
                    rd2 = sRD[4*pb+2], rd3 = sRD[4*pb+3];
        ngd.x = Ngf[(4*pb+0)*44 + u] * rd0;
        ngd.y = Ngf[(4*pb+1)*44 + u] * rd1;
        ngd.z = Ngf[(4*pb+2)*44 + u] * rd2;
        ngd.w = Ngf[(4*pb+3)*44 + u] * rd3;
        sGc[0][u*11 + pb] = ngd;                     // G0 = D^-1 Ng (column-major)
        if (u < GS) {
            const float4 v4 = *(const float4*)&val[sys*NLOC + u*PARAM + 4*pb];
            vd.x = v4.x * rd0; vd.y = v4.y * rd1; vd.z = v4.z * rd2; vd.w = v4.w * rd3;
            sXv[0][u*10 + pb] = vd;                  // c0 = D^-1 v
        }
    }
    __syncthreads();

    // ---- inner sweeps: G <- Ngd - S'off G ;  c <- Vd - S'off c ----
    for (int s = 0; s < INNER; ++s) {
        const int cur = s & 1, nxt = cur ^ 1;
        float4 accG = ngd;
        float4 accC = vd;
        const float4* gcol = &sGc[cur][u * 11];
        #pragma unroll
        for (int k = 0; k < 10; ++k) {
            const float4 g = gcol[k];
            accG.x -= sr0[k].x*g.x + sr0[k].y*g.y + sr0[k].z*g.z + sr0[k].w*g.w;
            accG.y -= sr1[k].x*g.x + sr1[k].y*g.y + sr1[k].z*g.z + sr1[k].w*g.w;
            accG.z -= sr2[k].x*g.x + sr2[k].y*g.y + sr2[k].z*g.z + sr2[k].w*g.w;
            accG.w -= sr3[k].x*g.x + sr3[k].y*g.y + sr3[k].z*g.z + sr3[k].w*g.w;
        }
        if (u < GS) {
            const float4* ccol = &sXv[cur][u * 10];
            #pragma unroll
            for (int k = 0; k < 10; ++k) {
                const float4 c = ccol[k];
                accC.x -= sr0[k].x*c.x + sr0[k].y*c.y + sr0[k].z*c.z + sr0[k].w*c.w;
                accC.y -= sr1[k].x*c.x + sr1[k].y*c.y + sr1[k].z*c.z + sr1[k].w*c.w;
                accC.z -= sr2[k].x*c.x + sr2[k].y*c.y + sr2[k].z*c.z + sr2[k].w*c.w;
                accC.w -= sr3[k].x*c.x + sr3[k].y*c.y + sr3[k].z*c.z + sr3[k].w*c.w;
            }
        }
        sGc[nxt][u*11 + pb] = accG;
        if (u < GS) sXv[nxt][u*10 + pb] = accC;
        __syncthreads();
    }
    const int fin = INNER & 1;   // final G / c buffer index (== 1 for odd INNER)

    // ---- outer-loop registers: G rows p, p+20; c values; M row ----
    const int i = t / GS;        // block-row 0..19
    const int p = t % GS;        // component 0..19; partner p+20
    float4 gr0[10], gr1[10];
    {
        const float* Gf = (const float*)sGc[fin];    // G[r][q] at [q*44 + r]
        #pragma unroll
        for (int k = 0; k < 10; ++k) {
            gr0[k].x = Gf[(4*k+0)*44 + p];  gr0[k].y = Gf[(4*k+1)*44 + p];
            gr0[k].z = Gf[(4*k+2)*44 + p];  gr0[k].w = Gf[(4*k+3)*44 + p];
            gr1[k].x = Gf[(4*k+0)*44 + p+20]; gr1[k].y = Gf[(4*k+1)*44 + p+20];
            gr1[k].z = Gf[(4*k+2)*44 + p+20]; gr1[k].w = Gf[(4*k+3)*44 + p+20];
        }
    }
    const float c0 = ((const float*)sXv[fin])[i*PARAM + p];
    const float c1 = ((const float*)sXv[fin])[i*PARAM + p + 20];
    float mrow[GS];
    if (t < 200) {
        const int zi = t / 10;
        #pragma unroll
        for (int j = 0; j < GS; ++j) mrow[j] = sM[zi*GS + j];
    }
    // (reads only — data is final behind the last inner barrier; x0 = c already in sXv[fin])

    int cur = fin;
    for (int it = 0; it < OUTER; ++it) {
        // phase 1: Z[zi][cc4] = sum_j M[zi,j] * X[j][cc4]
        if (t < 200) {
            const int zi = t / 10, cc = t - (t/10)*10;
            const float4* X4 = sXv[cur];
            float4 acc = make_float4(0.f, 0.f, 0.f, 0.f);
            #pragma unroll
            for (int j = 0; j < GS; ++j) {
                const float  m = mrow[j];
                const float4 x = X4[j*10 + cc];
                acc.x += m*x.x; acc.y += m*x.y; acc.z += m*x.z; acc.w += m*x.w;
            }
            sZ[t] = acc;
        }
        __syncthreads();
        // phase 2: x'_{i,p} = c - Grow_p · Z_i  (two outputs share Z_i reads)
        const float4* Z4 = &sZ[i*10];
        float a0 = 0.f, a1 = 0.f;
        #pragma unroll
        for (int k = 0; k < 10; ++k) {
            const float4 z = Z4[k];
            a0 += gr0[k].x*z.x + gr0[k].y*z.y + gr0[k].z*z.z + gr0[k].w*z.w;
            a1 += gr1[k].x*z.x + gr1[k].y*z.y + gr1[k].z*z.z + gr1[k].w*z.w;
        }
        const float x0n = c0 - a0, x1n = c1 - a1;
        if (it == OUTER - 1) {
            // epilogue: advrelu(lo=-1,hi=1) == clip
            out[sys*NLOC + i*PARAM + p   ] = fminf(fmaxf(x0n, -1.f), 1.f);
            out[sys*NLOC + i*PARAM + p+20] = fminf(fmaxf(x1n, -1.f), 1.f);
        } else {
            ((float*)sXv[cur ^ 1])[i*PARAM + p   ] = x0n;
            ((float*)sXv[cur ^ 1])[i*PARAM + p+20] = x1n;
            __syncthreads();
            cur ^= 1;
        }
    }
}

extern "C" void kernel_launch(void* const* d_in, const int* in_sizes, int n_in,
                              void* d_out, int out_size, void* d_ws, size_t ws_size,
                              hipStream_t stream) {
    const float* mat = (const float*)d_in[0];  // 8*10*20*20 = 32000
    const float* val = (const float*)d_in[1];  // 8*10*20*40 = 64000
    const float* S   = (const float*)d_in[2];  // 40*40
    const float* Ng  = (const float*)d_in[3];  // 40*40
    float* out = (float*)d_out;                // 64000 f32

    gliam_solve<<<NSYS, NTH, 0, stream>>>(mat, val, S, Ng, out);
}